// Round 15
// baseline (185.346 us; speedup 1.0000x reference)
//
#include <hip/hip_runtime.h>
#include <hip/hip_bf16.h>

#define N_IMG 4
#define C_CH 256
#define H_DIM 64
#define W_DIM 64
#define HW 4096
#define NCLASS 20
#define NHEADS 4
#define HD 64   // channels per head

typedef __attribute__((ext_vector_type(8))) short short8;
typedef __attribute__((ext_vector_type(4))) float f32x4;

__device__ __forceinline__ ushort f2bf(float f) {
    unsigned u = __float_as_uint(f);
    u += 0x7FFFu + ((u >> 16) & 1u);   // RNE
    return (ushort)(u >> 16);
}

// ---------------------------------------------------------------------------
// PHASE A (256 threads): [0,1024) att_inf | [1024,1280) att_dif_unmasked |
// [1280,2320) zero_border | [2320,2576) mask_m | [2576,3600) plane_sum |
// [3600,4112) prep_w.  Heavy branches first so they dispatch earliest.
// att branches use DEFERRED OOB masking: accumulate unmasked via clamped
// offsets (pure fma inner loop), multiply s[j] by msk[j] once at the end —
// bit-identical (finite*0 = +-0; exp(+-0 - mx) identical) and ~1/3 less VALU.
__global__ __launch_bounds__(256) void k_phaseA(
    ushort* __restrict__ xinp,
    const float* __restrict__ feats, const float* __restrict__ wgap,
    const int* __restrict__ label,
    float* __restrict__ mask, unsigned* __restrict__ mmax,
    float* __restrict__ S_f,
    const float* __restrict__ Kten, const float* __restrict__ Qten,
    float* __restrict__ att_inf, float* __restrict__ att_dif,
    const float* __restrict__ cw, ushort* __restrict__ wt3) {
    __shared__ __align__(16) float smem[1600];   // 6.4 KB (max of branches)
    int b = blockIdx.x;
    int t = threadIdx.x;

    if (b < 1024) {
        // ---- att_inf (5x5, dil 3): patch=Q, center=K; tap-quarter split ----
        int a = b >> 8;
        int bb = b & 255;
        int n = bb >> 6, h = bb & 63;
        int w = t & 63;
        int kq = t >> 6;
        float* att_s = smem;           // [25][64]

        int k0 = (kq == 0) ? 0 : (1 + kq * 6);
        int nk = (kq == 0) ? 7 : 6;
        int offc[7]; float msk[7];
#pragma unroll
        for (int j = 0; j < 7; j++) {
            int k = k0 + ((j < nk) ? j : 0);
            int y = h + (k / 5 - 2) * 3, x = w + (k % 5 - 2) * 3;
            bool v = (y >= 0 && y < 64 && x >= 0 && x < 64) && (j < nk);
            offc[j] = v ? y * 64 + x : 0;
            msk[j] = v ? 1.f : 0.f;
        }
        float s[7];
#pragma unroll
        for (int j = 0; j < 7; j++) s[j] = 0.f;
        const float* cp = Kten + ((size_t)(n * C_CH + a * HD)) * HW + h * W_DIM + w;
        const float* pp = Qten + ((size_t)(n * C_CH + a * HD)) * HW;
        for (int c4 = 0; c4 < 64; c4 += 4) {
            float cen[4];
            float pv[4][7];
#pragma unroll
            for (int u = 0; u < 4; u++)
                cen[u] = cp[(size_t)(c4 + u) * HW];
#pragma unroll
            for (int u = 0; u < 4; u++) {
                const float* pc = pp + (size_t)(c4 + u) * HW;
#pragma unroll
                for (int j = 0; j < 7; j++)
                    if (j < nk) pv[u][j] = pc[offc[j]];
            }
#pragma unroll
            for (int u = 0; u < 4; u++)
#pragma unroll
                for (int j = 0; j < 7; j++)
                    if (j < nk) s[j] += pv[u][j] * cen[u];   // unmasked fma
        }
#pragma unroll
        for (int j = 0; j < 7; j++)
            if (j < nk) att_s[(k0 + j) * 64 + w] = s[j] * msk[j];  // deferred mask
        __syncthreads();
        if (t < 64) {
            float v[25];
            float mx = -1e30f;
#pragma unroll
            for (int k = 0; k < 25; k++) { v[k] = att_s[k * 64 + t]; mx = fmaxf(mx, v[k]); }
            float sum = 0.f;
#pragma unroll
            for (int k = 0; k < 25; k++) { v[k] = __expf(v[k] - mx); sum += v[k]; }
            float inv = 1.0f / sum;
#pragma unroll
            for (int k = 0; k < 25; k++)
                att_inf[((size_t)(a * 25 + k) * N_IMG + n) * HW + h * 64 + t] = v[k] * inv;
        }
    } else if (b < 1280) {
        // ---- att_dif UNMASKED (3x3, dil 6): patch=K, center=Q. Thread =
        // (w,a) owns all 9 taps x 64 ch; per-thread softmax; no LDS/atomics.
        // Mask factor applied later in prep_fused at the source pixel. ----
        int bb = b - 1024;
        int n = bb >> 6, h = bb & 63;
        int w = t & 63, a = t >> 6;
        int offc[9]; float msk[9];
#pragma unroll
        for (int k = 0; k < 9; k++) {
            int y = h + (k / 3 - 1) * 6, x = w + (k % 3 - 1) * 6;
            bool v = (y >= 0 && y < 64 && x >= 0 && x < 64);
            offc[k] = v ? y * 64 + x : 0;
            msk[k] = v ? 1.f : 0.f;
        }
        float s[9];
#pragma unroll
        for (int k = 0; k < 9; k++) s[k] = 0.f;
        const float* cp = Qten + ((size_t)(n * C_CH + a * HD)) * HW + h * W_DIM + w;
        const float* pp = Kten + ((size_t)(n * C_CH + a * HD)) * HW;
        for (int c4 = 0; c4 < 64; c4 += 4) {
            float cen[4];
            float pv[4][9];
#pragma unroll
            for (int u = 0; u < 4; u++)
                cen[u] = cp[(size_t)(c4 + u) * HW];
#pragma unroll
            for (int u = 0; u < 4; u++) {
                const float* pc = pp + (size_t)(c4 + u) * HW;
#pragma unroll
                for (int k = 0; k < 9; k++)
                    pv[u][k] = pc[offc[k]];
            }
#pragma unroll
            for (int u = 0; u < 4; u++)
#pragma unroll
                for (int k = 0; k < 9; k++)
                    s[k] += pv[u][k] * cen[u];               // unmasked fma
        }
#pragma unroll
        for (int k = 0; k < 9; k++) s[k] *= msk[k];          // deferred mask
        float mx = -1e30f;
#pragma unroll
        for (int k = 0; k < 9; k++) mx = fmaxf(mx, s[k]);
        float sum = 0.f;
#pragma unroll
        for (int k = 0; k < 9; k++) { s[k] = __expf(s[k] - mx); sum += s[k]; }
        float inv = 1.0f / sum;
#pragma unroll
        for (int k = 0; k < 9; k++)
            att_dif[((size_t)(a * 9 + k) * N_IMG + n) * HW + h * W_DIM + w] = s[k] * inv;
    } else if (b < 2320) {
        // ---- zero halo border of xinp [4][66][66][512] ----
        int bb = b - 1280;
        int n = bb / 260, seg = bb % 260;
        size_t base;
        if (seg < 66)       base = ((size_t)(n * 66 + 0) * 66 + seg) * 512;
        else if (seg < 132) base = ((size_t)(n * 66 + 65) * 66 + (seg - 66)) * 512;
        else {
            int c = seg - 132;
            int r = 1 + (c >> 1), x = (c & 1) ? 65 : 0;
            base = ((size_t)(n * 66 + r) * 66 + x) * 512;
        }
        ((unsigned*)(xinp + base))[t] = 0u;
    } else if (b < 2576) {
        // ---- mask_m: raw mask + per-image max ----
        int bb = b - 2320;
        int n = bb >> 6, h = bb & 63;
        int w = t & 63, cq = t >> 6;
        float* wrow = smem;            // 256
        float* part = smem + 256;      // 4*64
        int lab = label[n];
        wrow[t] = wgap[lab * C_CH + t];
        __syncthreads();
        const float* fp = feats + ((size_t)(n * C_CH + cq * 64)) * HW + h * W_DIM + w;
        float acc = 0.f;
        for (int c = 0; c < 64; c++) acc += fp[(size_t)c * HW] * wrow[cq * 64 + c];
        part[cq * 64 + w] = acc;
        __syncthreads();
        if (cq == 0) {
            float m = fmaxf(part[w] + part[64 + w] + part[128 + w] + part[192 + w], 0.f);
            mask[n * HW + h * W_DIM + w] = m;
            for (int off = 32; off; off >>= 1) m = fmaxf(m, __shfl_down(m, off, 64));
            if (w == 0) atomicMax(&mmax[n], __float_as_uint(m));
        }
    } else if (b < 3600) {
        // ---- plane_sum (f32x4 vectorized) ----
        int nc = b - 2576;
        const f32x4* p4 = (const f32x4*)(feats + (size_t)nc * HW);
        f32x4 a4 = (f32x4){0.f, 0.f, 0.f, 0.f};
        for (int i = t; i < HW / 4; i += 256) a4 += p4[i];
        float s = a4[0] + a4[1] + a4[2] + a4[3];
        float* red = smem;
        for (int off = 32; off; off >>= 1) s += __shfl_down(s, off, 64);
        int wid = t >> 6;
        if ((t & 63) == 0) red[wid] = s;
        __syncthreads();
        if (t == 0) S_f[nc] = red[0] + red[1] + red[2] + red[3];
    } else {
        // ---- prep_w: conv_w -> wt3[icc][tap][lq][oc][8] coalesced bf16 ----
        int idx = (b - 3600) * 256 + t;   // oc*512+ic
        const float* p = cw + (size_t)idx * 9;
        int ic = idx & 511;
        int oc = idx >> 9;
        int icc = ic >> 5, lq = (ic & 31) >> 3, pos = ic & 7;
#pragma unroll
        for (int kk = 0; kk < 9; kk++)
            wt3[((((size_t)(icc * 9 + kk)) * 4 + lq) * 256 + oc) * 8 + pos] = f2bf(p[kk]);
    }
}

// ---------------------------------------------------------------------------
// PHASE B: scatter_w only (tiny). W_a[n,y,x] = sum_k att_inf[a,k,(y-dy,x-dx)]
__global__ __launch_bounds__(256) void k_scatter_w(const float* __restrict__ att,
                                                   float* __restrict__ W) {
    int b = blockIdx.x;   // n*64 + y
    int n = b >> 6, y = b & 63;
    int t = threadIdx.x;
    int x = t & 63, a = t >> 6;
    float s = 0.f;
#pragma unroll
    for (int k = 0; k < 25; k++) {
        int sy = y - (k / 5 - 2) * 3, sx = x - (k % 5 - 2) * 3;
        if (sy >= 0 && sy < 64 && sx >= 0 && sx < 64)
            s += att[((size_t)(a * 25 + k) * N_IMG + n) * HW + sy * 64 + sx];
    }
    W[((size_t)a * N_IMG + n) * HW + y * 64 + x] = s;
}

// ---------------------------------------------------------------------------
// PHASE C (256 threads): blocks [0,1024) wsum | [1024,5120) prep_fused
// (att_dif is unmasked; mask factor applied here at the source pixel).
__global__ __launch_bounds__(256) void k_phaseC(
    const float* __restrict__ feats, const float* __restrict__ Wpl,
    float* __restrict__ S_r,
    const float* __restrict__ mask, const unsigned* __restrict__ mmax,
    const float* __restrict__ att, ushort* __restrict__ xinp) {
    __shared__ __align__(16) char smemc[31488];
    int b = blockIdx.x;
    int t = threadIdx.x;

    if (b < 1024) {
        // ---- wsum: S_r[n,c] = sum_px feats * W ----
        int nc = b;
        int n = nc >> 8, c = nc & 255;
        int a = c >> 6;
        const f32x4* p4 = (const f32x4*)(feats + (size_t)nc * HW);
        const f32x4* w4 = (const f32x4*)(Wpl + ((size_t)a * N_IMG + n) * HW);
        f32x4 a4 = (f32x4){0.f, 0.f, 0.f, 0.f};
        for (int i = t; i < HW / 4; i += 256) {
            f32x4 u = p4[i], v = w4[i];
            a4 += u * v;
        }
        float s = a4[0] + a4[1] + a4[2] + a4[3];
        float* red = (float*)smemc;
        for (int off = 32; off; off >>= 1) s += __shfl_down(s, off, 64);
        int wid = t >> 6;
        if ((t & 63) == 0) red[wid] = s;
        __syncthreads();
        if (t == 0) S_r[nc] = red[0] + red[1] + red[2] + red[3];
    } else {
        // ---- prep_fused ----
        int idx = b - 1024;            // 4096 = 64y * 4n * 16g
        int y = idx & 63, n = (idx >> 6) & 3, g = idx >> 8;
        int x = t & 63, cg = t >> 6;
        float (*ftile)[32][64] = (float(*)[32][64])smemc;            // 24.0 KB
        float (*att_s)[64]     = (float(*)[64])(smemc + 24576);      //  2.3 KB
        ushort (*sx)[36]       = (ushort(*)[36])(smemc + 26880);     //  4.5 KB
        short8 pk;
        if (g < 8) {
            int cbase = g * 32 + cg * 8;
            float mnorm = fmaxf(__uint_as_float(mmax[n]), 1.0f);
            float mval = mask[n * HW + y * 64 + x] / mnorm;
            const float* fp = feats + ((size_t)(n * C_CH + cbase)) * HW + y * 64 + x;
            float v[8];
#pragma unroll
            for (int i = 0; i < 8; i++) v[i] = fp[(size_t)i * HW];
#pragma unroll
            for (int i = 0; i < 8; i++) pk[i] = (short)f2bf(v[i] * mval);
        } else {
            int gd = g - 8;
            int a = gd >> 1;
            int cd = gd * 32;
            float mnorm = fmaxf(__uint_as_float(mmax[n]), 1.0f);
            float rmn = 1.0f / mnorm;
            for (int idx2 = t; idx2 < 9 * 64; idx2 += 256) {
                int k = idx2 >> 6, w = idx2 & 63;
                int sy = y - (k / 3 - 1) * 6;
                att_s[k][w] = (sy >= 0 && sy < 64)
                    ? att[((size_t)(a * 9 + k) * N_IMG + n) * HW + sy * 64 + w]
                      * (mask[n * HW + sy * 64 + w] * rmn)
                    : 0.f;
            }
            const float* fb = feats + ((size_t)(n * C_CH + cd)) * HW;
#pragma unroll
            for (int i = 0; i < 24; i++) {
                int idx2 = t + 256 * i;
                int r = idx2 >> 11, c = (idx2 >> 6) & 31, xx = idx2 & 63;
                int ry = y + (r - 1) * 6;
                ((float*)ftile)[idx2] = (ry >= 0 && ry < 64)
                    ? fb[(size_t)c * HW + ry * 64 + xx] : 0.f;
            }
            __syncthreads();
#pragma unroll
            for (int cl = 0; cl < 8; cl++) {
                int c = cg * 8 + cl;
                float v = 0.f;
#pragma unroll
                for (int k = 0; k < 9; k++) {
                    int sxk = x - (k % 3 - 1) * 6;
                    if (sxk >= 0 && sxk < 64)
                        v += ftile[2 - k / 3][c][sxk] * att_s[k][sxk];
                }
                pk[cl] = (short)f2bf(v);
            }
        }
        __syncthreads();
        *(short8*)&sx[x][cg * 8] = pk;
        __syncthreads();
        int px = t >> 2, j = t & 3;
        short8 v8 = *(const short8*)&sx[px][j * 8];
        int chb = (g < 8) ? g * 32 : 256 + (g - 8) * 32;
        *(short8*)(xinp + ((size_t)((n * 66 + y + 1) * 66 + px + 1)) * 512 + chb + j * 8) = v8;
    }
}

// ---------------------------------------------------------------------------
// both GAP predictions (separate launch to keep conv codegen clean)
__global__ void k_pred2(const float* __restrict__ S_f, const float* __restrict__ wg,
                        const float* __restrict__ S_r, const float* __restrict__ wgr,
                        float* __restrict__ out) {
    int idx = threadIdx.x;
    if (idx < N_IMG * NCLASS) {
        int n = idx / NCLASS, k = idx % NCLASS;
        float s = 0.f;
        for (int c = 0; c < C_CH; c++) s += wg[k * C_CH + c] * S_f[n * C_CH + c];
        out[idx] = s * (1.0f / HW);
    } else if (idx < 2 * N_IMG * NCLASS) {
        int j = idx - N_IMG * NCLASS;
        int n = j / NCLASS, k = j % NCLASS;
        float s = 0.f;
        for (int c = 0; c < C_CH; c++) s += wgr[k * C_CH + c] * S_r[n * C_CH + c];
        out[idx] = s * (1.0f / HW);
    }
}

// ---------------------------------------------------------------------------
// MFMA implicit-GEMM conv (R12-verbatim, measured 48.3-48.7 us): in-block
// split-K (512 threads, two 4-wave halves on icc 0-7 / 8-15, LDS acc-reduce
// epilogue) + chunk-XOR swizzled LDS + T14 reg-staging + coalesced A + XCD
// swizzle. No extra branches/args — keeps the hot-loop codegen untouched.
#define LDS_PXW 32   // ushorts per px row (64B = 4 chunks; swizzle, no pad)
__global__ __launch_bounds__(512, 4) void k_conv_mfma(
    const ushort* __restrict__ xinp,  // [4][66][66][512] bf16, border-zeroed
    const ushort* __restrict__ wt3,   // [16][9][4][256][8] bf16 coalesced
    const float* __restrict__ cb,
    float* __restrict__ out) {
    int t512 = threadIdx.x;
    int half = t512 >> 8;             // 0: iccs 0..7, 1: iccs 8..15
    int th   = t512 & 255;            // thread id within half
    int lane = t512 & 63;
    int wid  = (t512 >> 6) & 3;       // wave within half
    int bid = blockIdx.x;
    int w   = (bid & 7) * 64 + (bid >> 3);
    int och = w & 1;
    int y0  = (w >> 1) & 63;
    int n   = w >> 7;
    int ocw = och * 128 + wid * 32;
    int l15 = lane & 15, lq = lane >> 4;

    // chunk layout: chunk = (r*4 + j)*66 + px, 16B per chunk; 792 chunks/buf
    __shared__ ushort lds[2][2][792 * 8];   // [half][buf] 50,688 B total

    f32x4 acc[2][4];
#pragma unroll
    for (int m = 0; m < 2; m++)
#pragma unroll
        for (int xs = 0; xs < 4; xs++) acc[m][xs] = (f32x4){0.f, 0.f, 0.f, 0.f};

    int s0 = th, s1 = th + 256, s2 = th + 512, s3 = th + 768;
    short8 g0, g1, g2, g3;
    int icb = half * 8;

#define SWZ_OFF(R, PX, J) (((((((R) * 66 + (PX)) << 2) | (J)) ^ ((PX) & 7)) << 3))

#define STAGE_LOAD(ICC)                                                              \
    {                                                                                \
        int icc_ = (ICC);                                                            \
        { int r = s0 / 264, rem = s0 % 264, px = rem >> 2, j = rem & 3;              \
          g0 = *(const short8*)(xinp + ((size_t)((n * 66 + y0 + r) * 66 + px)) * 512 \
                                 + icc_ * 32 + j * 8); }                             \
        { int r = s1 / 264, rem = s1 % 264, px = rem >> 2, j = rem & 3;              \
          g1 = *(const short8*)(xinp + ((size_t)((n * 66 + y0 + r) * 66 + px)) * 512 \
                                 + icc_ * 32 + j * 8); }                             \
        { int r = s2 / 264, rem = s2 % 264, px = rem >> 2, j = rem & 3;              \
          g2 = *(const short8*)(xinp + ((size_t)((n * 66 + y0 + r) * 66 + px)) * 512 \
                                 + icc_ * 32 + j * 8); }                             \
        if (s3 < 792) {                                                              \
          int r = s3 / 264, rem = s3 % 264, px = rem >> 2, j = rem & 3;              \
          g3 = *(const short8*)(xinp + ((size_t)((n * 66 + y0 + r) * 66 + px)) * 512 \
                                 + icc_ * 32 + j * 8); }                             \
    }

#define STAGE_WRITE(BUF)                                                             \
    {                                                                                \
        ushort* lb = &lds[half][BUF][0];                                             \
        { int r = s0 / 264, rem = s0 % 264, px = rem >> 2, j = rem & 3;              \
          *(short8*)&lb[SWZ_OFF(r, px, j)] = g0; }                                   \
        { int r = s1 / 264, rem = s1 % 264, px = rem >> 2, j = rem & 3;              \
          *(short8*)&lb[SWZ_OFF(r, px, j)] = g1; }                                   \
        { int r = s2 / 264, rem = s2 % 264, px = rem >> 2, j = rem & 3;              \
          *(short8*)&lb[SWZ_OFF(r, px, j)] = g2; }                                   \
        if (s3 < 792) {                                                              \
          int r = s3 / 264, rem = s3 % 264, px = rem >> 2, j = rem & 3;              \
          *(short8*)&lb[SWZ_OFF(r, px, j)] = g3; }                                   \
    }

    STAGE_LOAD(icb);
    STAGE_WRITE(0);
    __syncthreads();

    int cur = 0;
    for (int it = 0; it < 8; it++) {
        int icc = icb + it;
        if (it < 7) STAGE_LOAD(icc + 1);
        const ushort* lp = &lds[half][cur][0];
        const ushort* am0 = wt3 + (size_t)icc * 73728 + lq * 2048 + (ocw + l15) * 8;
        const ushort* am1 = am0 + 128;   // +16 oc
        short8 a0c = *(const short8*)(am0);
        short8 a1c = *(const short8*)(am1);
        short8 a0n = *(const short8*)(am0 + 8192);
        short8 a1n = *(const short8*)(am1 + 8192);
#pragma unroll
        for (int kk = 0; kk < 9; kk++) {
            short8 a0nn, a1nn;
            if (kk < 7) {
                a0nn = *(const short8*)(am0 + (kk + 2) * 8192);
                a1nn = *(const short8*)(am1 + (kk + 2) * 8192);
            }
            int ky = kk / 3, kx = kk % 3;
            int kxl = kx + l15;
            const ushort* lrow = lp + SWZ_OFF(ky, kxl, lq);
            short8 b0 = *(const short8*)(lrow);
            short8 b1 = *(const short8*)(lrow + 16 * LDS_PXW);
            short8 b2 = *(const short8*)(lrow + 32 * LDS_PXW);
            short8 b3 = *(const short8*)(lrow + 48 * LDS_PXW);
            acc[0][0] = __builtin_amdgcn_mfma_f32_16x16x32_bf16(a0c, b0, acc[0][0], 0, 0, 0);
            acc[1][0] = __builtin_amdgcn_mfma_f32_16x16x32_bf16(a1c, b0, acc[1][0], 0, 0, 0);
            acc[0][1] = __builtin_amdgcn_mfma_f32_16x16x32_bf16(a0c, b1, acc[0][1], 0, 0, 0);
            acc[1][1] = __builtin_amdgcn_mfma_f32_16x16x32_bf16(a1c, b1, acc[1][1], 0, 0, 0);
            acc[0][2] = __builtin_amdgcn_mfma_f32_16x16x32_bf16(a0c, b2, acc[0][2], 0, 0, 0);
            acc[1][2] = __builtin_amdgcn_mfma_f32_16x16x32_bf16(a1c, b2, acc[1][2], 0, 0, 0);
            acc[0][3] = __builtin_amdgcn_mfma_f32_16x16x32_bf16(a0c, b3, acc[0][3], 0, 0, 0);
            acc[1][3] = __builtin_amdgcn_mfma_f32_16x16x32_bf16(a1c, b3, acc[1][3], 0, 0, 0);
            a0c = a0n; a1c = a1n; a0n = a0nn; a1n = a1nn;
        }
        if (it < 7) {
            STAGE_WRITE(cur ^ 1);
            __syncthreads();
            cur ^= 1;
        }
    }

    float* red = (float*)&lds[0][0][0];   // 32 * 256 * 4B = 32,768 B
    __syncthreads();
    if (half == 1) {
#pragma unroll
        for (int m = 0; m < 2; m++)
#pragma unroll
            for (int xs = 0; xs < 4; xs++)
#pragma unroll
                for (int r = 0; r < 4; r++)
                    red[(((m * 4 + xs) * 4) + r) * 256 + th] = acc[m][xs][r];
    }
    __syncthreads();
    if (half == 0) {
#pragma unroll
        for (int m = 0; m < 2; m++) {
#pragma unroll
            for (int r = 0; r < 4; r++) {
                int oc = ocw + m * 16 + lq * 4 + r;
                float bias = cb[oc];
                float* op = out + ((size_t)(n * 256 + oc)) * HW + y0 * 64 + l15;
#pragma unroll
                for (int xs = 0; xs < 4; xs++)
                    op[xs * 16] = acc[m][xs][r] + red[(((m * 4 + xs) * 4) + r) * 256 + th] + bias;
            }
        }
    }
#undef STAGE_LOAD
#undef STAGE_WRITE
#undef SWZ_OFF
}

// ---------------------------------------------------------------------------
extern "C" void kernel_launch(void* const* d_in, const int* in_sizes, int n_in,
                              void* d_out, int out_size, void* d_ws, size_t ws_size,
                              hipStream_t stream) {
    const float* feats  = (const float*)d_in[0];
    const float* Kten   = (const float*)d_in[1];
    const float* Qten   = (const float*)d_in[2];
    const float* w_gap  = (const float*)d_in[3];
    const float* w_gapr = (const float*)d_in[4];
    const float* conv_w = (const float*)d_in[5];
    const float* conv_b = (const float*)d_in[6];
    const int*   label  = (const int*)d_in[7];
    float* ob           = (float*)d_out;

    float* ws = (float*)d_ws;
    float*    mask    = ws;                         // 16384
    unsigned* mmax    = (unsigned*)(ws + 16384);    // 4
    float*    S_f     = ws + 16384 + 4;             // 1024
    float*    S_r     = S_f + 1024;                 // 1024
    float*    att_inf = S_r + 1024;                 // 25*4*16384 = 1,638,400
    float*    Wpl     = att_inf + 1638400;          // 4*4*4096 = 65,536
    float*    att_dif = Wpl + 65536;                // 589,824
    ushort*   xinp    = (ushort*)(att_dif + 589824); // 8,921,088 ushorts
    ushort*   wt3     = xinp + 8921088;              // 1,179,648 ushorts

    const int NXT = N_IMG * C_CH * HW;              // 4,194,304

    hipMemsetAsync(mmax, 0, N_IMG * sizeof(unsigned), stream);

    // A: att_inf | att_dif_unmasked | zero_border | mask_m | plane_sum | prep_w
    k_phaseA<<<4112, 256, 0, stream>>>(xinp, feats, w_gap, label, mask, mmax,
                                       S_f, Kten, Qten, att_inf, att_dif,
                                       conv_w, wt3);
    // B: scatter_w only (tiny)
    k_scatter_w<<<N_IMG * H_DIM, 256, 0, stream>>>(att_inf, Wpl);
    // C: wsum | prep_fused (mask applied on att load)
    k_phaseC<<<5120, 256, 0, stream>>>(feats, Wpl, S_r, mask, mmax, att_dif, xinp);

    // conv (clean R12 codegen), then both GAP heads
    k_conv_mfma<<<512, 512, 0, stream>>>(xinp, wt3, conv_b, ob);
    k_pred2<<<1, 192, 0, stream>>>(S_f, w_gap, S_r, w_gapr, ob + NXT);
}

// Round 16
// 143.509 us; speedup vs baseline: 1.2915x; 1.2915x over previous
//
#include <hip/hip_runtime.h>
#include <hip/hip_bf16.h>

#define N_IMG 4
#define C_CH 256
#define H_DIM 64
#define W_DIM 64
#define HW 4096
#define NCLASS 20
#define NHEADS 4
#define HD 64   // channels per head

typedef __attribute__((ext_vector_type(8))) short short8;
typedef __attribute__((ext_vector_type(4))) float f32x4;

__device__ __forceinline__ ushort f2bf(float f) {
    unsigned u = __float_as_uint(f);
    u += 0x7FFFu + ((u >> 16) & 1u);   // RNE
    return (ushort)(u >> 16);
}

// ---------------------------------------------------------------------------
// PHASE A (256 threads): [0,1024) att_inf | [1024,1280) att_dif_unmasked |
// [1280,2320) zero_border | [2320,2576) mask_m | [2576,3600) plane_sum |
// [3600,4112) prep_w.  Heavy branches first so they dispatch earliest.
// NOTE (R15 lesson): keep the msk[] multiply INSIDE the inner loops — the
// "deferred mask" variant lets the compiler pipeline to 256 VGPRs, collapsing
// occupancy for the whole fused kernel (53 -> 103 us). Do not "optimize".
__global__ __launch_bounds__(256) void k_phaseA(
    ushort* __restrict__ xinp,
    const float* __restrict__ feats, const float* __restrict__ wgap,
    const int* __restrict__ label,
    float* __restrict__ mask, unsigned* __restrict__ mmax,
    float* __restrict__ S_f,
    const float* __restrict__ Kten, const float* __restrict__ Qten,
    float* __restrict__ att_inf, float* __restrict__ att_dif,
    const float* __restrict__ cw, ushort* __restrict__ wt3) {
    __shared__ __align__(16) float smem[1600];   // 6.4 KB (max of branches)
    int b = blockIdx.x;
    int t = threadIdx.x;

    if (b < 1024) {
        // ---- att_inf (5x5, dil 3): patch=Q, center=K; tap-quarter split ----
        int a = b >> 8;
        int bb = b & 255;
        int n = bb >> 6, h = bb & 63;
        int w = t & 63;
        int kq = t >> 6;
        float* att_s = smem;           // [25][64]

        int k0 = (kq == 0) ? 0 : (1 + kq * 6);
        int nk = (kq == 0) ? 7 : 6;
        int offc[7]; float msk[7];
#pragma unroll
        for (int j = 0; j < 7; j++) {
            int k = k0 + ((j < nk) ? j : 0);
            int y = h + (k / 5 - 2) * 3, x = w + (k % 5 - 2) * 3;
            bool v = (y >= 0 && y < 64 && x >= 0 && x < 64) && (j < nk);
            offc[j] = v ? y * 64 + x : 0;
            msk[j] = v ? 1.f : 0.f;
        }
        float s[7];
#pragma unroll
        for (int j = 0; j < 7; j++) s[j] = 0.f;
        const float* cp = Kten + ((size_t)(n * C_CH + a * HD)) * HW + h * W_DIM + w;
        const float* pp = Qten + ((size_t)(n * C_CH + a * HD)) * HW;
        for (int c4 = 0; c4 < 64; c4 += 4) {
            float cen[4];
            float pv[4][7];
#pragma unroll
            for (int u = 0; u < 4; u++)
                cen[u] = cp[(size_t)(c4 + u) * HW];
#pragma unroll
            for (int u = 0; u < 4; u++) {
                const float* pc = pp + (size_t)(c4 + u) * HW;
#pragma unroll
                for (int j = 0; j < 7; j++)
                    if (j < nk) pv[u][j] = pc[offc[j]];
            }
#pragma unroll
            for (int u = 0; u < 4; u++)
#pragma unroll
                for (int j = 0; j < 7; j++)
                    if (j < nk) s[j] += pv[u][j] * msk[j] * cen[u];
        }
#pragma unroll
        for (int j = 0; j < 7; j++)
            if (j < nk) att_s[(k0 + j) * 64 + w] = s[j];
        __syncthreads();
        if (t < 64) {
            float v[25];
            float mx = -1e30f;
#pragma unroll
            for (int k = 0; k < 25; k++) { v[k] = att_s[k * 64 + t]; mx = fmaxf(mx, v[k]); }
            float sum = 0.f;
#pragma unroll
            for (int k = 0; k < 25; k++) { v[k] = __expf(v[k] - mx); sum += v[k]; }
            float inv = 1.0f / sum;
#pragma unroll
            for (int k = 0; k < 25; k++)
                att_inf[((size_t)(a * 25 + k) * N_IMG + n) * HW + h * 64 + t] = v[k] * inv;
        }
    } else if (b < 1280) {
        // ---- att_dif UNMASKED (3x3, dil 6): patch=K, center=Q. Thread =
        // (w,a) owns all 9 taps x 64 ch; per-thread softmax; no LDS/atomics.
        // Mask factor applied later in prep_fused at the source pixel. ----
        int bb = b - 1024;
        int n = bb >> 6, h = bb & 63;
        int w = t & 63, a = t >> 6;
        int offc[9]; float msk[9];
#pragma unroll
        for (int k = 0; k < 9; k++) {
            int y = h + (k / 3 - 1) * 6, x = w + (k % 3 - 1) * 6;
            bool v = (y >= 0 && y < 64 && x >= 0 && x < 64);
            offc[k] = v ? y * 64 + x : 0;
            msk[k] = v ? 1.f : 0.f;
        }
        float s[9];
#pragma unroll
        for (int k = 0; k < 9; k++) s[k] = 0.f;
        const float* cp = Qten + ((size_t)(n * C_CH + a * HD)) * HW + h * W_DIM + w;
        const float* pp = Kten + ((size_t)(n * C_CH + a * HD)) * HW;
        for (int c4 = 0; c4 < 64; c4 += 4) {
            float cen[4];
            float pv[4][9];
#pragma unroll
            for (int u = 0; u < 4; u++)
                cen[u] = cp[(size_t)(c4 + u) * HW];
#pragma unroll
            for (int u = 0; u < 4; u++) {
                const float* pc = pp + (size_t)(c4 + u) * HW;
#pragma unroll
                for (int k = 0; k < 9; k++)
                    pv[u][k] = pc[offc[k]];
            }
#pragma unroll
            for (int u = 0; u < 4; u++)
#pragma unroll
                for (int k = 0; k < 9; k++)
                    s[k] += pv[u][k] * msk[k] * cen[u];
        }
        float mx = -1e30f;
#pragma unroll
        for (int k = 0; k < 9; k++) mx = fmaxf(mx, s[k]);
        float sum = 0.f;
#pragma unroll
        for (int k = 0; k < 9; k++) { s[k] = __expf(s[k] - mx); sum += s[k]; }
        float inv = 1.0f / sum;
#pragma unroll
        for (int k = 0; k < 9; k++)
            att_dif[((size_t)(a * 9 + k) * N_IMG + n) * HW + h * W_DIM + w] = s[k] * inv;
    } else if (b < 2320) {
        // ---- zero halo border of xinp [4][66][66][512] ----
        int bb = b - 1280;
        int n = bb / 260, seg = bb % 260;
        size_t base;
        if (seg < 66)       base = ((size_t)(n * 66 + 0) * 66 + seg) * 512;
        else if (seg < 132) base = ((size_t)(n * 66 + 65) * 66 + (seg - 66)) * 512;
        else {
            int c = seg - 132;
            int r = 1 + (c >> 1), x = (c & 1) ? 65 : 0;
            base = ((size_t)(n * 66 + r) * 66 + x) * 512;
        }
        ((unsigned*)(xinp + base))[t] = 0u;
    } else if (b < 2576) {
        // ---- mask_m: raw mask + per-image max ----
        int bb = b - 2320;
        int n = bb >> 6, h = bb & 63;
        int w = t & 63, cq = t >> 6;
        float* wrow = smem;            // 256
        float* part = smem + 256;      // 4*64
        int lab = label[n];
        wrow[t] = wgap[lab * C_CH + t];
        __syncthreads();
        const float* fp = feats + ((size_t)(n * C_CH + cq * 64)) * HW + h * W_DIM + w;
        float acc = 0.f;
        for (int c = 0; c < 64; c++) acc += fp[(size_t)c * HW] * wrow[cq * 64 + c];
        part[cq * 64 + w] = acc;
        __syncthreads();
        if (cq == 0) {
            float m = fmaxf(part[w] + part[64 + w] + part[128 + w] + part[192 + w], 0.f);
            mask[n * HW + h * W_DIM + w] = m;
            for (int off = 32; off; off >>= 1) m = fmaxf(m, __shfl_down(m, off, 64));
            if (w == 0) atomicMax(&mmax[n], __float_as_uint(m));
        }
    } else if (b < 3600) {
        // ---- plane_sum ----
        int nc = b - 2576;
        const float* p = feats + (size_t)nc * HW;
        float s = 0.f;
        for (int i = t; i < HW; i += 256) s += p[i];
        float* red = smem;
        for (int off = 32; off; off >>= 1) s += __shfl_down(s, off, 64);
        int wid = t >> 6;
        if ((t & 63) == 0) red[wid] = s;
        __syncthreads();
        if (t == 0) S_f[nc] = red[0] + red[1] + red[2] + red[3];
    } else {
        // ---- prep_w: conv_w -> wt3[icc][tap][lq][oc][8] coalesced bf16 ----
        int idx = (b - 3600) * 256 + t;   // oc*512+ic
        const float* p = cw + (size_t)idx * 9;
        int ic = idx & 511;
        int oc = idx >> 9;
        int icc = ic >> 5, lq = (ic & 31) >> 3, pos = ic & 7;
#pragma unroll
        for (int kk = 0; kk < 9; kk++)
            wt3[((((size_t)(icc * 9 + kk)) * 4 + lq) * 256 + oc) * 8 + pos] = f2bf(p[kk]);
    }
}

// ---------------------------------------------------------------------------
// PHASE B: scatter_w only (tiny). W_a[n,y,x] = sum_k att_inf[a,k,(y-dy,x-dx)]
__global__ __launch_bounds__(256) void k_scatter_w(const float* __restrict__ att,
                                                   float* __restrict__ W) {
    int b = blockIdx.x;   // n*64 + y
    int n = b >> 6, y = b & 63;
    int t = threadIdx.x;
    int x = t & 63, a = t >> 6;
    float s = 0.f;
#pragma unroll
    for (int k = 0; k < 25; k++) {
        int sy = y - (k / 5 - 2) * 3, sx = x - (k % 5 - 2) * 3;
        if (sy >= 0 && sy < 64 && sx >= 0 && sx < 64)
            s += att[((size_t)(a * 25 + k) * N_IMG + n) * HW + sy * 64 + sx];
    }
    W[((size_t)a * N_IMG + n) * HW + y * 64 + x] = s;
}

// ---------------------------------------------------------------------------
// PHASE C (256 threads): blocks [0,1024) wsum | [1024,5120) prep_fused
// (att_dif is unmasked; mask factor applied here at the source pixel).
__global__ __launch_bounds__(256) void k_phaseC(
    const float* __restrict__ feats, const float* __restrict__ Wpl,
    float* __restrict__ S_r,
    const float* __restrict__ mask, const unsigned* __restrict__ mmax,
    const float* __restrict__ att, ushort* __restrict__ xinp) {
    __shared__ __align__(16) char smemc[31488];
    int b = blockIdx.x;
    int t = threadIdx.x;

    if (b < 1024) {
        // ---- wsum: S_r[n,c] = sum_px feats * W ----
        int nc = b;
        int n = nc >> 8, c = nc & 255;
        int a = c >> 6;
        const f32x4* p4 = (const f32x4*)(feats + (size_t)nc * HW);
        const f32x4* w4 = (const f32x4*)(Wpl + ((size_t)a * N_IMG + n) * HW);
        f32x4 a4 = (f32x4){0.f, 0.f, 0.f, 0.f};
        for (int i = t; i < HW / 4; i += 256) {
            f32x4 u = p4[i], v = w4[i];
            a4 += u * v;
        }
        float s = a4[0] + a4[1] + a4[2] + a4[3];
        float* red = (float*)smemc;
        for (int off = 32; off; off >>= 1) s += __shfl_down(s, off, 64);
        int wid = t >> 6;
        if ((t & 63) == 0) red[wid] = s;
        __syncthreads();
        if (t == 0) S_r[nc] = red[0] + red[1] + red[2] + red[3];
    } else {
        // ---- prep_fused ----
        int idx = b - 1024;            // 4096 = 64y * 4n * 16g
        int y = idx & 63, n = (idx >> 6) & 3, g = idx >> 8;
        int x = t & 63, cg = t >> 6;
        float (*ftile)[32][64] = (float(*)[32][64])smemc;            // 24.0 KB
        float (*att_s)[64]     = (float(*)[64])(smemc + 24576);      //  2.3 KB
        ushort (*sx)[36]       = (ushort(*)[36])(smemc + 26880);     //  4.5 KB
        short8 pk;
        if (g < 8) {
            int cbase = g * 32 + cg * 8;
            float mnorm = fmaxf(__uint_as_float(mmax[n]), 1.0f);
            float mval = mask[n * HW + y * 64 + x] / mnorm;
            const float* fp = feats + ((size_t)(n * C_CH + cbase)) * HW + y * 64 + x;
            float v[8];
#pragma unroll
            for (int i = 0; i < 8; i++) v[i] = fp[(size_t)i * HW];
#pragma unroll
            for (int i = 0; i < 8; i++) pk[i] = (short)f2bf(v[i] * mval);
        } else {
            int gd = g - 8;
            int a = gd >> 1;
            int cd = gd * 32;
            float mnorm = fmaxf(__uint_as_float(mmax[n]), 1.0f);
            float rmn = 1.0f / mnorm;
            for (int idx2 = t; idx2 < 9 * 64; idx2 += 256) {
                int k = idx2 >> 6, w = idx2 & 63;
                int sy = y - (k / 3 - 1) * 6;
                att_s[k][w] = (sy >= 0 && sy < 64)
                    ? att[((size_t)(a * 9 + k) * N_IMG + n) * HW + sy * 64 + w]
                      * (mask[n * HW + sy * 64 + w] * rmn)
                    : 0.f;
            }
            const float* fb = feats + ((size_t)(n * C_CH + cd)) * HW;
#pragma unroll
            for (int i = 0; i < 24; i++) {
                int idx2 = t + 256 * i;
                int r = idx2 >> 11, c = (idx2 >> 6) & 31, xx = idx2 & 63;
                int ry = y + (r - 1) * 6;
                ((float*)ftile)[idx2] = (ry >= 0 && ry < 64)
                    ? fb[(size_t)c * HW + ry * 64 + xx] : 0.f;
            }
            __syncthreads();
#pragma unroll
            for (int cl = 0; cl < 8; cl++) {
                int c = cg * 8 + cl;
                float v = 0.f;
#pragma unroll
                for (int k = 0; k < 9; k++) {
                    int sxk = x - (k % 3 - 1) * 6;
                    if (sxk >= 0 && sxk < 64)
                        v += ftile[2 - k / 3][c][sxk] * att_s[k][sxk];
                }
                pk[cl] = (short)f2bf(v);
            }
        }
        __syncthreads();
        *(short8*)&sx[x][cg * 8] = pk;
        __syncthreads();
        int px = t >> 2, j = t & 3;
        short8 v8 = *(const short8*)&sx[px][j * 8];
        int chb = (g < 8) ? g * 32 : 256 + (g - 8) * 32;
        *(short8*)(xinp + ((size_t)((n * 66 + y + 1) * 66 + px + 1)) * 512 + chb + j * 8) = v8;
    }
}

// ---------------------------------------------------------------------------
// both GAP predictions (separate launch to keep conv codegen clean)
__global__ void k_pred2(const float* __restrict__ S_f, const float* __restrict__ wg,
                        const float* __restrict__ S_r, const float* __restrict__ wgr,
                        float* __restrict__ out) {
    int idx = threadIdx.x;
    if (idx < N_IMG * NCLASS) {
        int n = idx / NCLASS, k = idx % NCLASS;
        float s = 0.f;
        for (int c = 0; c < C_CH; c++) s += wg[k * C_CH + c] * S_f[n * C_CH + c];
        out[idx] = s * (1.0f / HW);
    } else if (idx < 2 * N_IMG * NCLASS) {
        int j = idx - N_IMG * NCLASS;
        int n = j / NCLASS, k = j % NCLASS;
        float s = 0.f;
        for (int c = 0; c < C_CH; c++) s += wgr[k * C_CH + c] * S_r[n * C_CH + c];
        out[idx] = s * (1.0f / HW);
    }
}

// ---------------------------------------------------------------------------
// MFMA implicit-GEMM conv (R12-verbatim, measured 48.3-48.7 us): in-block
// split-K (512 threads, two 4-wave halves on icc 0-7 / 8-15, LDS acc-reduce
// epilogue) + chunk-XOR swizzled LDS + T14 reg-staging + coalesced A + XCD
// swizzle. No extra branches/args — keeps the hot-loop codegen untouched.
#define LDS_PXW 32   // ushorts per px row (64B = 4 chunks; swizzle, no pad)
__global__ __launch_bounds__(512, 4) void k_conv_mfma(
    const ushort* __restrict__ xinp,  // [4][66][66][512] bf16, border-zeroed
    const ushort* __restrict__ wt3,   // [16][9][4][256][8] bf16 coalesced
    const float* __restrict__ cb,
    float* __restrict__ out) {
    int t512 = threadIdx.x;
    int half = t512 >> 8;             // 0: iccs 0..7, 1: iccs 8..15
    int th   = t512 & 255;            // thread id within half
    int lane = t512 & 63;
    int wid  = (t512 >> 6) & 3;       // wave within half
    int bid = blockIdx.x;
    int w   = (bid & 7) * 64 + (bid >> 3);
    int och = w & 1;
    int y0  = (w >> 1) & 63;
    int n   = w >> 7;
    int ocw = och * 128 + wid * 32;
    int l15 = lane & 15, lq = lane >> 4;

    // chunk layout: chunk = (r*4 + j)*66 + px, 16B per chunk; 792 chunks/buf
    __shared__ ushort lds[2][2][792 * 8];   // [half][buf] 50,688 B total

    f32x4 acc[2][4];
#pragma unroll
    for (int m = 0; m < 2; m++)
#pragma unroll
        for (int xs = 0; xs < 4; xs++) acc[m][xs] = (f32x4){0.f, 0.f, 0.f, 0.f};

    int s0 = th, s1 = th + 256, s2 = th + 512, s3 = th + 768;
    short8 g0, g1, g2, g3;
    int icb = half * 8;

#define SWZ_OFF(R, PX, J) (((((((R) * 66 + (PX)) << 2) | (J)) ^ ((PX) & 7)) << 3))

#define STAGE_LOAD(ICC)                                                              \
    {                                                                                \
        int icc_ = (ICC);                                                            \
        { int r = s0 / 264, rem = s0 % 264, px = rem >> 2, j = rem & 3;              \
          g0 = *(const short8*)(xinp + ((size_t)((n * 66 + y0 + r) * 66 + px)) * 512 \
                                 + icc_ * 32 + j * 8); }                             \
        { int r = s1 / 264, rem = s1 % 264, px = rem >> 2, j = rem & 3;              \
          g1 = *(const short8*)(xinp + ((size_t)((n * 66 + y0 + r) * 66 + px)) * 512 \
                                 + icc_ * 32 + j * 8); }                             \
        { int r = s2 / 264, rem = s2 % 264, px = rem >> 2, j = rem & 3;              \
          g2 = *(const short8*)(xinp + ((size_t)((n * 66 + y0 + r) * 66 + px)) * 512 \
                                 + icc_ * 32 + j * 8); }                             \
        if (s3 < 792) {                                                              \
          int r = s3 / 264, rem = s3 % 264, px = rem >> 2, j = rem & 3;              \
          g3 = *(const short8*)(xinp + ((size_t)((n * 66 + y0 + r) * 66 + px)) * 512 \
                                 + icc_ * 32 + j * 8); }                             \
    }

#define STAGE_WRITE(BUF)                                                             \
    {                                                                                \
        ushort* lb = &lds[half][BUF][0];                                             \
        { int r = s0 / 264, rem = s0 % 264, px = rem >> 2, j = rem & 3;              \
          *(short8*)&lb[SWZ_OFF(r, px, j)] = g0; }                                   \
        { int r = s1 / 264, rem = s1 % 264, px = rem >> 2, j = rem & 3;              \
          *(short8*)&lb[SWZ_OFF(r, px, j)] = g1; }                                   \
        { int r = s2 / 264, rem = s2 % 264, px = rem >> 2, j = rem & 3;              \
          *(short8*)&lb[SWZ_OFF(r, px, j)] = g2; }                                   \
        if (s3 < 792) {                                                              \
          int r = s3 / 264, rem = s3 % 264, px = rem >> 2, j = rem & 3;              \
          *(short8*)&lb[SWZ_OFF(r, px, j)] = g3; }                                   \
    }

    STAGE_LOAD(icb);
    STAGE_WRITE(0);
    __syncthreads();

    int cur = 0;
    for (int it = 0; it < 8; it++) {
        int icc = icb + it;
        if (it < 7) STAGE_LOAD(icc + 1);
        const ushort* lp = &lds[half][cur][0];
        const ushort* am0 = wt3 + (size_t)icc * 73728 + lq * 2048 + (ocw + l15) * 8;
        const ushort* am1 = am0 + 128;   // +16 oc
        short8 a0c = *(const short8*)(am0);
        short8 a1c = *(const short8*)(am1);
        short8 a0n = *(const short8*)(am0 + 8192);
        short8 a1n = *(const short8*)(am1 + 8192);
#pragma unroll
        for (int kk = 0; kk < 9; kk++) {
            short8 a0nn, a1nn;
            if (kk < 7) {
                a0nn = *(const short8*)(am0 + (kk + 2) * 8192);
                a1nn = *(const short8*)(am1 + (kk + 2) * 8192);
            }
            int ky = kk / 3, kx = kk % 3;
            int kxl = kx + l15;
            const ushort* lrow = lp + SWZ_OFF(ky, kxl, lq);
            short8 b0 = *(const short8*)(lrow);
            short8 b1 = *(const short8*)(lrow + 16 * LDS_PXW);
            short8 b2 = *(const short8*)(lrow + 32 * LDS_PXW);
            short8 b3 = *(const short8*)(lrow + 48 * LDS_PXW);
            acc[0][0] = __builtin_amdgcn_mfma_f32_16x16x32_bf16(a0c, b0, acc[0][0], 0, 0, 0);
            acc[1][0] = __builtin_amdgcn_mfma_f32_16x16x32_bf16(a1c, b0, acc[1][0], 0, 0, 0);
            acc[0][1] = __builtin_amdgcn_mfma_f32_16x16x32_bf16(a0c, b1, acc[0][1], 0, 0, 0);
            acc[1][1] = __builtin_amdgcn_mfma_f32_16x16x32_bf16(a1c, b1, acc[1][1], 0, 0, 0);
            acc[0][2] = __builtin_amdgcn_mfma_f32_16x16x32_bf16(a0c, b2, acc[0][2], 0, 0, 0);
            acc[1][2] = __builtin_amdgcn_mfma_f32_16x16x32_bf16(a1c, b2, acc[1][2], 0, 0, 0);
            acc[0][3] = __builtin_amdgcn_mfma_f32_16x16x32_bf16(a0c, b3, acc[0][3], 0, 0, 0);
            acc[1][3] = __builtin_amdgcn_mfma_f32_16x16x32_bf16(a1c, b3, acc[1][3], 0, 0, 0);
            a0c = a0n; a1c = a1n; a0n = a0nn; a1n = a1nn;
        }
        if (it < 7) {
            STAGE_WRITE(cur ^ 1);
            __syncthreads();
            cur ^= 1;
        }
    }

    float* red = (float*)&lds[0][0][0];   // 32 * 256 * 4B = 32,768 B
    __syncthreads();
    if (half == 1) {
#pragma unroll
        for (int m = 0; m < 2; m++)
#pragma unroll
            for (int xs = 0; xs < 4; xs++)
#pragma unroll
                for (int r = 0; r < 4; r++)
                    red[(((m * 4 + xs) * 4) + r) * 256 + th] = acc[m][xs][r];
    }
    __syncthreads();
    if (half == 0) {
#pragma unroll
        for (int m = 0; m < 2; m++) {
#pragma unroll
            for (int r = 0; r < 4; r++) {
                int oc = ocw + m * 16 + lq * 4 + r;
                float bias = cb[oc];
                float* op = out + ((size_t)(n * 256 + oc)) * HW + y0 * 64 + l15;
#pragma unroll
                for (int xs = 0; xs < 4; xs++)
                    op[xs * 16] = acc[m][xs][r] + red[(((m * 4 + xs) * 4) + r) * 256 + th] + bias;
            }
        }
    }
#undef STAGE_LOAD
#undef STAGE_WRITE
#undef SWZ_OFF
}

// ---------------------------------------------------------------------------
extern "C" void kernel_launch(void* const* d_in, const int* in_sizes, int n_in,
                              void* d_out, int out_size, void* d_ws, size_t ws_size,
                              hipStream_t stream) {
    const float* feats  = (const float*)d_in[0];
    const float* Kten   = (const float*)d_in[1];
    const float* Qten   = (const float*)d_in[2];
    const float* w_gap  = (const float*)d_in[3];
    const float* w_gapr = (const float*)d_in[4];
    const float* conv_w = (const float*)d_in[5];
    const float* conv_b = (const float*)d_in[6];
    const int*   label  = (const int*)d_in[7];
    float* ob           = (float*)d_out;

    float* ws = (float*)d_ws;
    float*    mask    = ws;                         // 16384
    unsigned* mmax    = (unsigned*)(ws + 16384);    // 4
    float*    S_f     = ws + 16384 + 4;             // 1024
    float*    S_r     = S_f + 1024;                 // 1024
    float*    att_inf = S_r + 1024;                 // 25*4*16384 = 1,638,400
    float*    Wpl     = att_inf + 1638400;          // 4*4*4096 = 65,536
    float*    att_dif = Wpl + 65536;                // 589,824
    ushort*   xinp    = (ushort*)(att_dif + 589824); // 8,921,088 ushorts
    ushort*   wt3     = xinp + 8921088;              // 1,179,648 ushorts

    const int NXT = N_IMG * C_CH * HW;              // 4,194,304

    hipMemsetAsync(mmax, 0, N_IMG * sizeof(unsigned), stream);

    // A: att_inf | att_dif_unmasked | zero_border | mask_m | plane_sum | prep_w
    k_phaseA<<<4112, 256, 0, stream>>>(xinp, feats, w_gap, label, mask, mmax,
                                       S_f, Kten, Qten, att_inf, att_dif,
                                       conv_w, wt3);
    // B: scatter_w only (tiny)
    k_scatter_w<<<N_IMG * H_DIM, 256, 0, stream>>>(att_inf, Wpl);
    // C: wsum | prep_fused (mask applied on att load)
    k_phaseC<<<5120, 256, 0, stream>>>(feats, Wpl, S_r, mask, mmax, att_dif, xinp);

    // conv (clean R12 codegen), then both GAP heads
    k_conv_mfma<<<512, 512, 0, stream>>>(xinp, wt3, conv_b, ob);
    k_pred2<<<1, 192, 0, stream>>>(S_f, w_gap, S_r, w_gapr, ob + NXT);
}

// Round 17
// 140.471 us; speedup vs baseline: 1.3195x; 1.0216x over previous
//
#include <hip/hip_runtime.h>
#include <hip/hip_bf16.h>

#define N_IMG 4
#define C_CH 256
#define H_DIM 64
#define W_DIM 64
#define HW 4096
#define NCLASS 20
#define NHEADS 4
#define HD 64   // channels per head

typedef __attribute__((ext_vector_type(8))) short short8;
typedef __attribute__((ext_vector_type(4))) float f32x4;

__device__ __forceinline__ ushort f2bf(float f) {
    unsigned u = __float_as_uint(f);
    u += 0x7FFFu + ((u >> 16) & 1u);   // RNE
    return (ushort)(u >> 16);
}

// ---------------------------------------------------------------------------
// PHASE A (256 threads): [0,1280) XCD-chunked att group (4x att_inf heads +
// 1x att_dif per (n,h) group; remap wk=(b&7)*160+(b>>3), g=wk/5, m=wk%5 puts
// all gather blocks sharing K/Q rows on ONE XCD's L2) | [1280,2320)
// zero_border | [2320,2576) mask_m | [2576,3600) plane_sum | [3600,4112)
// prep_w.
// NOTE (R15 lesson): keep the msk[] multiply INSIDE the inner loops — the
// "deferred mask" variant lets the compiler pipeline to 256 VGPRs, collapsing
// occupancy for the whole fused kernel (53 -> 103 us). Do not "optimize".
__global__ __launch_bounds__(256) void k_phaseA(
    ushort* __restrict__ xinp,
    const float* __restrict__ feats, const float* __restrict__ wgap,
    const int* __restrict__ label,
    float* __restrict__ mask, unsigned* __restrict__ mmax,
    float* __restrict__ S_f,
    const float* __restrict__ Kten, const float* __restrict__ Qten,
    float* __restrict__ att_inf, float* __restrict__ att_dif,
    const float* __restrict__ cw, ushort* __restrict__ wt3) {
    __shared__ __align__(16) float smem[1600];   // 6.4 KB (max of branches)
    int b = blockIdx.x;
    int t = threadIdx.x;

    if (b < 1280) {
        // XCD-chunked remap: 1280 = 8 XCDs x 160; each XCD owns 32 (n,h)
        // groups of 5 blocks (4 att_inf heads + 1 att_dif) -> L2 reuse.
        int wk = (b & 7) * 160 + (b >> 3);
        int g = wk / 5, m = wk - g * 5;
        int n = g >> 6, h = g & 63;
        if (m < 4) {
            // ---- att_inf (5x5, dil 3): patch=Q, center=K; tap-quarter split
            int a = m;
            int w = t & 63;
            int kq = t >> 6;
            float* att_s = smem;           // [25][64]

            int k0 = (kq == 0) ? 0 : (1 + kq * 6);
            int nk = (kq == 0) ? 7 : 6;
            int offc[7]; float msk[7];
#pragma unroll
            for (int j = 0; j < 7; j++) {
                int k = k0 + ((j < nk) ? j : 0);
                int y = h + (k / 5 - 2) * 3, x = w + (k % 5 - 2) * 3;
                bool v = (y >= 0 && y < 64 && x >= 0 && x < 64) && (j < nk);
                offc[j] = v ? y * 64 + x : 0;
                msk[j] = v ? 1.f : 0.f;
            }
            float s[7];
#pragma unroll
            for (int j = 0; j < 7; j++) s[j] = 0.f;
            const float* cp = Kten + ((size_t)(n * C_CH + a * HD)) * HW + h * W_DIM + w;
            const float* pp = Qten + ((size_t)(n * C_CH + a * HD)) * HW;
            for (int c4 = 0; c4 < 64; c4 += 4) {
                float cen[4];
                float pv[4][7];
#pragma unroll
                for (int u = 0; u < 4; u++)
                    cen[u] = cp[(size_t)(c4 + u) * HW];
#pragma unroll
                for (int u = 0; u < 4; u++) {
                    const float* pc = pp + (size_t)(c4 + u) * HW;
#pragma unroll
                    for (int j = 0; j < 7; j++)
                        if (j < nk) pv[u][j] = pc[offc[j]];
                }
#pragma unroll
                for (int u = 0; u < 4; u++)
#pragma unroll
                    for (int j = 0; j < 7; j++)
                        if (j < nk) s[j] += pv[u][j] * msk[j] * cen[u];
            }
#pragma unroll
            for (int j = 0; j < 7; j++)
                if (j < nk) att_s[(k0 + j) * 64 + w] = s[j];
            __syncthreads();
            if (t < 64) {
                float v[25];
                float mx = -1e30f;
#pragma unroll
                for (int k = 0; k < 25; k++) { v[k] = att_s[k * 64 + t]; mx = fmaxf(mx, v[k]); }
                float sum = 0.f;
#pragma unroll
                for (int k = 0; k < 25; k++) { v[k] = __expf(v[k] - mx); sum += v[k]; }
                float inv = 1.0f / sum;
#pragma unroll
                for (int k = 0; k < 25; k++)
                    att_inf[((size_t)(a * 25 + k) * N_IMG + n) * HW + h * 64 + t] = v[k] * inv;
            }
        } else {
            // ---- att_dif UNMASKED (3x3, dil 6): patch=K, center=Q. Thread =
            // (w,a) owns all 9 taps x 64 ch; per-thread softmax; no LDS.
            // Mask factor applied later in prep_fused at the source pixel.
            int w = t & 63, a = t >> 6;
            int offc[9]; float msk[9];
#pragma unroll
            for (int k = 0; k < 9; k++) {
                int y = h + (k / 3 - 1) * 6, x = w + (k % 3 - 1) * 6;
                bool v = (y >= 0 && y < 64 && x >= 0 && x < 64);
                offc[k] = v ? y * 64 + x : 0;
                msk[k] = v ? 1.f : 0.f;
            }
            float s[9];
#pragma unroll
            for (int k = 0; k < 9; k++) s[k] = 0.f;
            const float* cp = Qten + ((size_t)(n * C_CH + a * HD)) * HW + h * W_DIM + w;
            const float* pp = Kten + ((size_t)(n * C_CH + a * HD)) * HW;
            for (int c4 = 0; c4 < 64; c4 += 4) {
                float cen[4];
                float pv[4][9];
#pragma unroll
                for (int u = 0; u < 4; u++)
                    cen[u] = cp[(size_t)(c4 + u) * HW];
#pragma unroll
                for (int u = 0; u < 4; u++) {
                    const float* pc = pp + (size_t)(c4 + u) * HW;
#pragma unroll
                    for (int k = 0; k < 9; k++)
                        pv[u][k] = pc[offc[k]];
                }
#pragma unroll
                for (int u = 0; u < 4; u++)
#pragma unroll
                    for (int k = 0; k < 9; k++)
                        s[k] += pv[u][k] * msk[k] * cen[u];
            }
            float mx = -1e30f;
#pragma unroll
            for (int k = 0; k < 9; k++) mx = fmaxf(mx, s[k]);
            float sum = 0.f;
#pragma unroll
            for (int k = 0; k < 9; k++) { s[k] = __expf(s[k] - mx); sum += s[k]; }
            float inv = 1.0f / sum;
#pragma unroll
            for (int k = 0; k < 9; k++)
                att_dif[((size_t)(a * 9 + k) * N_IMG + n) * HW + h * W_DIM + w] = s[k] * inv;
        }
    } else if (b < 2320) {
        // ---- zero halo border of xinp [4][66][66][512] ----
        int bb = b - 1280;
        int n = bb / 260, seg = bb % 260;
        size_t base;
        if (seg < 66)       base = ((size_t)(n * 66 + 0) * 66 + seg) * 512;
        else if (seg < 132) base = ((size_t)(n * 66 + 65) * 66 + (seg - 66)) * 512;
        else {
            int c = seg - 132;
            int r = 1 + (c >> 1), x = (c & 1) ? 65 : 0;
            base = ((size_t)(n * 66 + r) * 66 + x) * 512;
        }
        ((unsigned*)(xinp + base))[t] = 0u;
    } else if (b < 2576) {
        // ---- mask_m: raw mask + per-image max ----
        int bb = b - 2320;
        int n = bb >> 6, h = bb & 63;
        int w = t & 63, cq = t >> 6;
        float* wrow = smem;            // 256
        float* part = smem + 256;      // 4*64
        int lab = label[n];
        wrow[t] = wgap[lab * C_CH + t];
        __syncthreads();
        const float* fp = feats + ((size_t)(n * C_CH + cq * 64)) * HW + h * W_DIM + w;
        float acc = 0.f;
        for (int c = 0; c < 64; c++) acc += fp[(size_t)c * HW] * wrow[cq * 64 + c];
        part[cq * 64 + w] = acc;
        __syncthreads();
        if (cq == 0) {
            float m = fmaxf(part[w] + part[64 + w] + part[128 + w] + part[192 + w], 0.f);
            mask[n * HW + h * W_DIM + w] = m;
            for (int off = 32; off; off >>= 1) m = fmaxf(m, __shfl_down(m, off, 64));
            if (w == 0) atomicMax(&mmax[n], __float_as_uint(m));
        }
    } else if (b < 3600) {
        // ---- plane_sum ----
        int nc = b - 2576;
        const float* p = feats + (size_t)nc * HW;
        float s = 0.f;
        for (int i = t; i < HW; i += 256) s += p[i];
        float* red = smem;
        for (int off = 32; off; off >>= 1) s += __shfl_down(s, off, 64);
        int wid = t >> 6;
        if ((t & 63) == 0) red[wid] = s;
        __syncthreads();
        if (t == 0) S_f[nc] = red[0] + red[1] + red[2] + red[3];
    } else {
        // ---- prep_w: conv_w -> wt3[icc][tap][lq][oc][8] coalesced bf16 ----
        int idx = (b - 3600) * 256 + t;   // oc*512+ic
        const float* p = cw + (size_t)idx * 9;
        int ic = idx & 511;
        int oc = idx >> 9;
        int icc = ic >> 5, lq = (ic & 31) >> 3, pos = ic & 7;
#pragma unroll
        for (int kk = 0; kk < 9; kk++)
            wt3[((((size_t)(icc * 9 + kk)) * 4 + lq) * 256 + oc) * 8 + pos] = f2bf(p[kk]);
    }
}

// ---------------------------------------------------------------------------
// PHASE B: scatter_w only (tiny). W_a[n,y,x] = sum_k att_inf[a,k,(y-dy,x-dx)]
__global__ __launch_bounds__(256) void k_scatter_w(const float* __restrict__ att,
                                                   float* __restrict__ W) {
    int b = blockIdx.x;   // n*64 + y
    int n = b >> 6, y = b & 63;
    int t = threadIdx.x;
    int x = t & 63, a = t >> 6;
    float s = 0.f;
#pragma unroll
    for (int k = 0; k < 25; k++) {
        int sy = y - (k / 5 - 2) * 3, sx = x - (k % 5 - 2) * 3;
        if (sy >= 0 && sy < 64 && sx >= 0 && sx < 64)
            s += att[((size_t)(a * 25 + k) * N_IMG + n) * HW + sy * 64 + sx];
    }
    W[((size_t)a * N_IMG + n) * HW + y * 64 + x] = s;
}

// ---------------------------------------------------------------------------
// PHASE C (256 threads): blocks [0,1024) wsum | [1024,5120) prep_fused
// (att_dif is unmasked; mask factor applied here at the source pixel).
__global__ __launch_bounds__(256) void k_phaseC(
    const float* __restrict__ feats, const float* __restrict__ Wpl,
    float* __restrict__ S_r,
    const float* __restrict__ mask, const unsigned* __restrict__ mmax,
    const float* __restrict__ att, ushort* __restrict__ xinp) {
    __shared__ __align__(16) char smemc[31488];
    int b = blockIdx.x;
    int t = threadIdx.x;

    if (b < 1024) {
        // ---- wsum: S_r[n,c] = sum_px feats * W ----
        int nc = b;
        int n = nc >> 8, c = nc & 255;
        int a = c >> 6;
        const f32x4* p4 = (const f32x4*)(feats + (size_t)nc * HW);
        const f32x4* w4 = (const f32x4*)(Wpl + ((size_t)a * N_IMG + n) * HW);
        f32x4 a4 = (f32x4){0.f, 0.f, 0.f, 0.f};
        for (int i = t; i < HW / 4; i += 256) {
            f32x4 u = p4[i], v = w4[i];
            a4 += u * v;
        }
        float s = a4[0] + a4[1] + a4[2] + a4[3];
        float* red = (float*)smemc;
        for (int off = 32; off; off >>= 1) s += __shfl_down(s, off, 64);
        int wid = t >> 6;
        if ((t & 63) == 0) red[wid] = s;
        __syncthreads();
        if (t == 0) S_r[nc] = red[0] + red[1] + red[2] + red[3];
    } else {
        // ---- prep_fused ----
        int idx = b - 1024;            // 4096 = 64y * 4n * 16g
        int y = idx & 63, n = (idx >> 6) & 3, g = idx >> 8;
        int x = t & 63, cg = t >> 6;
        float (*ftile)[32][64] = (float(*)[32][64])smemc;            // 24.0 KB
        float (*att_s)[64]     = (float(*)[64])(smemc + 24576);      //  2.3 KB
        ushort (*sx)[36]       = (ushort(*)[36])(smemc + 26880);     //  4.5 KB
        short8 pk;
        if (g < 8) {
            int cbase = g * 32 + cg * 8;
            float mnorm = fmaxf(__uint_as_float(mmax[n]), 1.0f);
            float mval = mask[n * HW + y * 64 + x] / mnorm;
            const float* fp = feats + ((size_t)(n * C_CH + cbase)) * HW + y * 64 + x;
            float v[8];
#pragma unroll
            for (int i = 0; i < 8; i++) v[i] = fp[(size_t)i * HW];
#pragma unroll
            for (int i = 0; i < 8; i++) pk[i] = (short)f2bf(v[i] * mval);
        } else {
            int gd = g - 8;
            int a = gd >> 1;
            int cd = gd * 32;
            float mnorm = fmaxf(__uint_as_float(mmax[n]), 1.0f);
            float rmn = 1.0f / mnorm;
            for (int idx2 = t; idx2 < 9 * 64; idx2 += 256) {
                int k = idx2 >> 6, w = idx2 & 63;
                int sy = y - (k / 3 - 1) * 6;
                att_s[k][w] = (sy >= 0 && sy < 64)
                    ? att[((size_t)(a * 9 + k) * N_IMG + n) * HW + sy * 64 + w]
                      * (mask[n * HW + sy * 64 + w] * rmn)
                    : 0.f;
            }
            const float* fb = feats + ((size_t)(n * C_CH + cd)) * HW;
#pragma unroll
            for (int i = 0; i < 24; i++) {
                int idx2 = t + 256 * i;
                int r = idx2 >> 11, c = (idx2 >> 6) & 31, xx = idx2 & 63;
                int ry = y + (r - 1) * 6;
                ((float*)ftile)[idx2] = (ry >= 0 && ry < 64)
                    ? fb[(size_t)c * HW + ry * 64 + xx] : 0.f;
            }
            __syncthreads();
#pragma unroll
            for (int cl = 0; cl < 8; cl++) {
                int c = cg * 8 + cl;
                float v = 0.f;
#pragma unroll
                for (int k = 0; k < 9; k++) {
                    int sxk = x - (k % 3 - 1) * 6;
                    if (sxk >= 0 && sxk < 64)
                        v += ftile[2 - k / 3][c][sxk] * att_s[k][sxk];
                }
                pk[cl] = (short)f2bf(v);
            }
        }
        __syncthreads();
        *(short8*)&sx[x][cg * 8] = pk;
        __syncthreads();
        int px = t >> 2, j = t & 3;
        short8 v8 = *(const short8*)&sx[px][j * 8];
        int chb = (g < 8) ? g * 32 : 256 + (g - 8) * 32;
        *(short8*)(xinp + ((size_t)((n * 66 + y + 1) * 66 + px + 1)) * 512 + chb + j * 8) = v8;
    }
}

// ---------------------------------------------------------------------------
// both GAP predictions (separate launch to keep conv codegen clean)
__global__ void k_pred2(const float* __restrict__ S_f, const float* __restrict__ wg,
                        const float* __restrict__ S_r, const float* __restrict__ wgr,
                        float* __restrict__ out) {
    int idx = threadIdx.x;
    if (idx < N_IMG * NCLASS) {
        int n = idx / NCLASS, k = idx % NCLASS;
        float s = 0.f;
        for (int c = 0; c < C_CH; c++) s += wg[k * C_CH + c] * S_f[n * C_CH + c];
        out[idx] = s * (1.0f / HW);
    } else if (idx < 2 * N_IMG * NCLASS) {
        int j = idx - N_IMG * NCLASS;
        int n = j / NCLASS, k = j % NCLASS;
        float s = 0.f;
        for (int c = 0; c < C_CH; c++) s += wgr[k * C_CH + c] * S_r[n * C_CH + c];
        out[idx] = s * (1.0f / HW);
    }
}

// ---------------------------------------------------------------------------
// MFMA implicit-GEMM conv (R12-verbatim, measured 48.3-48.7 us): in-block
// split-K (512 threads, two 4-wave halves on icc 0-7 / 8-15, LDS acc-reduce
// epilogue) + chunk-XOR swizzled LDS + T14 reg-staging + coalesced A + XCD
// swizzle. No extra branches/args — keeps the hot-loop codegen untouched.
#define LDS_PXW 32   // ushorts per px row (64B = 4 chunks; swizzle, no pad)
__global__ __launch_bounds__(512, 4) void k_conv_mfma(
    const ushort* __restrict__ xinp,  // [4][66][66][512] bf16, border-zeroed
    const ushort* __restrict__ wt3,   // [16][9][4][256][8] bf16 coalesced
    const float* __restrict__ cb,
    float* __restrict__ out) {
    int t512 = threadIdx.x;
    int half = t512 >> 8;             // 0: iccs 0..7, 1: iccs 8..15
    int th   = t512 & 255;            // thread id within half
    int lane = t512 & 63;
    int wid  = (t512 >> 6) & 3;       // wave within half
    int bid = blockIdx.x;
    int w   = (bid & 7) * 64 + (bid >> 3);
    int och = w & 1;
    int y0  = (w >> 1) & 63;
    int n   = w >> 7;
    int ocw = och * 128 + wid * 32;
    int l15 = lane & 15, lq = lane >> 4;

    // chunk layout: chunk = (r*4 + j)*66 + px, 16B per chunk; 792 chunks/buf
    __shared__ ushort lds[2][2][792 * 8];   // [half][buf] 50,688 B total

    f32x4 acc[2][4];
#pragma unroll
    for (int m = 0; m < 2; m++)
#pragma unroll
        for (int xs = 0; xs < 4; xs++) acc[m][xs] = (f32x4){0.f, 0.f, 0.f, 0.f};

    int s0 = th, s1 = th + 256, s2 = th + 512, s3 = th + 768;
    short8 g0, g1, g2, g3;
    int icb = half * 8;

#define SWZ_OFF(R, PX, J) (((((((R) * 66 + (PX)) << 2) | (J)) ^ ((PX) & 7)) << 3))

#define STAGE_LOAD(ICC)                                                              \
    {                                                                                \
        int icc_ = (ICC);                                                            \
        { int r = s0 / 264, rem = s0 % 264, px = rem >> 2, j = rem & 3;              \
          g0 = *(const short8*)(xinp + ((size_t)((n * 66 + y0 + r) * 66 + px)) * 512 \
                                 + icc_ * 32 + j * 8); }                             \
        { int r = s1 / 264, rem = s1 % 264, px = rem >> 2, j = rem & 3;              \
          g1 = *(const short8*)(xinp + ((size_t)((n * 66 + y0 + r) * 66 + px)) * 512 \
                                 + icc_ * 32 + j * 8); }                             \
        { int r = s2 / 264, rem = s2 % 264, px = rem >> 2, j = rem & 3;              \
          g2 = *(const short8*)(xinp + ((size_t)((n * 66 + y0 + r) * 66 + px)) * 512 \
                                 + icc_ * 32 + j * 8); }                             \
        if (s3 < 792) {                                                              \
          int r = s3 / 264, rem = s3 % 264, px = rem >> 2, j = rem & 3;              \
          g3 = *(const short8*)(xinp + ((size_t)((n * 66 + y0 + r) * 66 + px)) * 512 \
                                 + icc_ * 32 + j * 8); }                             \
    }

#define STAGE_WRITE(BUF)                                                             \
    {                                                                                \
        ushort* lb = &lds[half][BUF][0];                                             \
        { int r = s0 / 264, rem = s0 % 264, px = rem >> 2, j = rem & 3;              \
          *(short8*)&lb[SWZ_OFF(r, px, j)] = g0; }                                   \
        { int r = s1 / 264, rem = s1 % 264, px = rem >> 2, j = rem & 3;              \
          *(short8*)&lb[SWZ_OFF(r, px, j)] = g1; }                                   \
        { int r = s2 / 264, rem = s2 % 264, px = rem >> 2, j = rem & 3;              \
          *(short8*)&lb[SWZ_OFF(r, px, j)] = g2; }                                   \
        if (s3 < 792) {                                                              \
          int r = s3 / 264, rem = s3 % 264, px = rem >> 2, j = rem & 3;              \
          *(short8*)&lb[SWZ_OFF(r, px, j)] = g3; }                                   \
    }

    STAGE_LOAD(icb);
    STAGE_WRITE(0);
    __syncthreads();

    int cur = 0;
    for (int it = 0; it < 8; it++) {
        int icc = icb + it;
        if (it < 7) STAGE_LOAD(icc + 1);
        const ushort* lp = &lds[half][cur][0];
        const ushort* am0 = wt3 + (size_t)icc * 73728 + lq * 2048 + (ocw + l15) * 8;
        const ushort* am1 = am0 + 128;   // +16 oc
        short8 a0c = *(const short8*)(am0);
        short8 a1c = *(const short8*)(am1);
        short8 a0n = *(const short8*)(am0 + 8192);
        short8 a1n = *(const short8*)(am1 + 8192);
#pragma unroll
        for (int kk = 0; kk < 9; kk++) {
            short8 a0nn, a1nn;
            if (kk < 7) {
                a0nn = *(const short8*)(am0 + (kk + 2) * 8192);
                a1nn = *(const short8*)(am1 + (kk + 2) * 8192);
            }
            int ky = kk / 3, kx = kk % 3;
            int kxl = kx + l15;
            const ushort* lrow = lp + SWZ_OFF(ky, kxl, lq);
            short8 b0 = *(const short8*)(lrow);
            short8 b1 = *(const short8*)(lrow + 16 * LDS_PXW);
            short8 b2 = *(const short8*)(lrow + 32 * LDS_PXW);
            short8 b3 = *(const short8*)(lrow + 48 * LDS_PXW);
            acc[0][0] = __builtin_amdgcn_mfma_f32_16x16x32_bf16(a0c, b0, acc[0][0], 0, 0, 0);
            acc[1][0] = __builtin_amdgcn_mfma_f32_16x16x32_bf16(a1c, b0, acc[1][0], 0, 0, 0);
            acc[0][1] = __builtin_amdgcn_mfma_f32_16x16x32_bf16(a0c, b1, acc[0][1], 0, 0, 0);
            acc[1][1] = __builtin_amdgcn_mfma_f32_16x16x32_bf16(a1c, b1, acc[1][1], 0, 0, 0);
            acc[0][2] = __builtin_amdgcn_mfma_f32_16x16x32_bf16(a0c, b2, acc[0][2], 0, 0, 0);
            acc[1][2] = __builtin_amdgcn_mfma_f32_16x16x32_bf16(a1c, b2, acc[1][2], 0, 0, 0);
            acc[0][3] = __builtin_amdgcn_mfma_f32_16x16x32_bf16(a0c, b3, acc[0][3], 0, 0, 0);
            acc[1][3] = __builtin_amdgcn_mfma_f32_16x16x32_bf16(a1c, b3, acc[1][3], 0, 0, 0);
            a0c = a0n; a1c = a1n; a0n = a0nn; a1n = a1nn;
        }
        if (it < 7) {
            STAGE_WRITE(cur ^ 1);
            __syncthreads();
            cur ^= 1;
        }
    }

    float* red = (float*)&lds[0][0][0];   // 32 * 256 * 4B = 32,768 B
    __syncthreads();
    if (half == 1) {
#pragma unroll
        for (int m = 0; m < 2; m++)
#pragma unroll
            for (int xs = 0; xs < 4; xs++)
#pragma unroll
                for (int r = 0; r < 4; r++)
                    red[(((m * 4 + xs) * 4) + r) * 256 + th] = acc[m][xs][r];
    }
    __syncthreads();
    if (half == 0) {
#pragma unroll
        for (int m = 0; m < 2; m++) {
#pragma unroll
            for (int r = 0; r < 4; r++) {
                int oc = ocw + m * 16 + lq * 4 + r;
                float bias = cb[oc];
                float* op = out + ((size_t)(n * 256 + oc)) * HW + y0 * 64 + l15;
#pragma unroll
                for (int xs = 0; xs < 4; xs++)
                    op[xs * 16] = acc[m][xs][r] + red[(((m * 4 + xs) * 4) + r) * 256 + th] + bias;
            }
        }
    }
#undef STAGE_LOAD
#undef STAGE_WRITE
#undef SWZ_OFF
}

// ---------------------------------------------------------------------------
extern "C" void kernel_launch(void* const* d_in, const int* in_sizes, int n_in,
                              void* d_out, int out_size, void* d_ws, size_t ws_size,
                              hipStream_t stream) {
    const float* feats  = (const float*)d_in[0];
    const float* Kten   = (const float*)d_in[1];
    const float* Qten   = (const float*)d_in[2];
    const float* w_gap  = (const float*)d_in[3];
    const float* w_gapr = (const float*)d_in[4];
    const float* conv_w = (const float*)d_in[5];
    const float* conv_b = (const float*)d_in[6];
    const int*   label  = (const int*)d_in[7];
    float* ob           = (float*)d_out;

    float* ws = (float*)d_ws;
    float*    mask    = ws;                         // 16384
    unsigned* mmax    = (unsigned*)(ws + 16384);    // 4
    float*    S_f     = ws + 16384 + 4;             // 1024
    float*    S_r     = S_f + 1024;                 // 1024
    float*    att_inf = S_r + 1024;                 // 25*4*16384 = 1,638,400
    float*    Wpl     = att_inf + 1638400;          // 4*4*4096 = 65,536
    float*    att_dif = Wpl + 65536;                // 589,824
    ushort*   xinp    = (ushort*)(att_dif + 589824); // 8,921,088 ushorts
    ushort*   wt3     = xinp + 8921088;              // 1,179,648 ushorts

    const int NXT = N_IMG * C_CH * HW;              // 4,194,304

    hipMemsetAsync(mmax, 0, N_IMG * sizeof(unsigned), stream);

    // A: att group (XCD-chunked) | zero_border | mask_m | plane_sum | prep_w
    k_phaseA<<<4112, 256, 0, stream>>>(xinp, feats, w_gap, label, mask, mmax,
                                       S_f, Kten, Qten, att_inf, att_dif,
                                       conv_w, wt3);
    // B: scatter_w only (tiny)
    k_scatter_w<<<N_IMG * H_DIM, 256, 0, stream>>>(att_inf, Wpl);
    // C: wsum | prep_fused (mask applied on att load)
    k_phaseC<<<5120, 256, 0, stream>>>(feats, Wpl, S_r, mask, mmax, att_dif, xinp);

    // conv (clean R12 codegen), then both GAP heads
    k_conv_mfma<<<512, 512, 0, stream>>>(xinp, wt3, conv_b, ob);
    k_pred2<<<1, 192, 0, stream>>>(S_f, w_gap, S_r, w_gapr, ob + NXT);
}